// Round 1
// baseline (545.362 us; speedup 1.0000x reference)
//
#include <hip/hip_runtime.h>
#include <math.h>

// Problem shape (fixed by reference setup_inputs):
//   images [32][256][64][64] fp32, words [32][32][768] fp32, mask [32][32] bool,
//   W [256][768] fp32, b [256] fp32
//   out0 weighted_words [32][256][64][64], out1 attn_out [32][32][64][64], fp32 concat.
#define B_   32
#define NC_  256
#define HW_  4096
#define MW_  32
#define E_   768
#define NEG_BIG -3.0e38f

// Workspace layout (float offsets). Total ~13.4 MB.
#define PART_OFF   0          // partial GEMM: 8 chunks * 32b * 32m * 256c = 2097152 floats
#define WP_OFF     2097152    // words_p [b][c][m]: 262144 floats
#define WT_OFF     2359296    // W transposed [e][c]: 196608 floats
#define WORDST_OFF 2555904    // words transposed [b][e][m]: 786432 floats
#define MASK_OFF   3342336    // normalized mask: 1024 ints

// ---------------------------------------------------------------------------
// Prep: tiled transposes (W 256x768 -> WT 768x256; words[b] 32x768 ->
// wordsT[b] 768x32) + mask normalization.
// Blocks 0..191: W transpose. 192..959: words transpose. 960: mask.
// ---------------------------------------------------------------------------
__global__ __launch_bounds__(256) void prep_kernel(
    const float* __restrict__ W, const float* __restrict__ words,
    const void* __restrict__ mask_raw,
    float* __restrict__ WT, float* __restrict__ wordsT,
    int* __restrict__ maskn) {
  const int tid = threadIdx.x;
  const int tx = tid & 31, ty = tid >> 5;
  if (blockIdx.x < 192) {
    // W: 32x32 tile transpose; tiles: 8 (c) x 24 (e)
    __shared__ float t[32][33];
    const int tc = blockIdx.x / 24, te = blockIdx.x % 24;
    const int c0 = tc * 32, e0 = te * 32;
#pragma unroll
    for (int k = 0; k < 4; ++k) {
      const int r = ty + 8 * k;
      t[r][tx] = W[(c0 + r) * E_ + e0 + tx];  // coalesced over tx
    }
    __syncthreads();
#pragma unroll
    for (int k = 0; k < 4; ++k) {
      const int r = ty + 8 * k;
      WT[(e0 + r) * NC_ + c0 + tx] = t[tx][r];  // coalesced over tx
    }
  } else if (blockIdx.x < 960) {
    // words[b]: 32(m) x 768(e) -> wordsT[b]: 768(e) x 32(m). tiles: 32 b x 24 e
    __shared__ float t[32][33];
    const int idx = blockIdx.x - 192;
    const int b = idx / 24, te = idx % 24;
    const int e0 = te * 32;
    const float* wsrc = words + (size_t)b * MW_ * E_;
    float* wdst = wordsT + (size_t)b * E_ * MW_;
#pragma unroll
    for (int k = 0; k < 4; ++k) {
      const int m = ty + 8 * k;
      t[m][tx] = wsrc[m * E_ + e0 + tx];        // coalesced over tx (e)
    }
    __syncthreads();
#pragma unroll
    for (int k = 0; k < 4; ++k) {
      const int e = ty + 8 * k;
      wdst[(e0 + e) * MW_ + tx] = t[tx][e];     // coalesced over tx (m)
    }
  } else {
    // Mask layout detection + normalize to int[1024].
    __shared__ int is_word;  // 1 if 4-byte-per-element layout (int32 or fp32)
    if (tid == 0) is_word = 1;
    __syncthreads();
    const int* mi = (const int*)mask_raw;
    const int v = mi[tid];  // reads only first 1024 bytes: safe for any layout
    if (v != 0 && v != 1 && v != 0x3F800000) is_word = 0;
    __syncthreads();
    if (is_word) {
#pragma unroll
      for (int j = 0; j < 4; ++j) { const int i = j * 256 + tid; maskn[i] = (mi[i] != 0); }
    } else {
      const unsigned char* mb = (const unsigned char*)mask_raw;
#pragma unroll
      for (int j = 0; j < 4; ++j) { const int i = j * 256 + tid; maskn[i] = (mb[i] != 0); }
    }
  }
}

// ---------------------------------------------------------------------------
// Stage 1a: words_p partials. Block = (batch, e-chunk of 96). lane = c.
// WT[e][c] coalesced vector load; wordsT[b][e][0..31] is wave-uniform AND
// contiguous -> 2x s_load_dwordx16 per e.
// ---------------------------------------------------------------------------
__global__ __launch_bounds__(256) void stage1_partial(
    const float* __restrict__ wordsT, const float* __restrict__ WT,
    float* __restrict__ part) {
  const int c = threadIdx.x;
  const int b = blockIdx.x >> 3;
  const int chunk = blockIdx.x & 7;
  const int e0 = chunk * 96;
  const float* wt = wordsT + (size_t)b * E_ * MW_;
  float acc[32];
#pragma unroll
  for (int m = 0; m < 32; ++m) acc[m] = 0.f;
#pragma unroll 2
  for (int e = e0; e < e0 + 96; ++e) {
    const float wv = WT[(size_t)e * NC_ + c];   // coalesced over lanes
    const float* wr = wt + e * MW_;             // uniform, contiguous
#pragma unroll
    for (int m = 0; m < 32; ++m) acc[m] = fmaf(wv, wr[m], acc[m]);
  }
  float* pp = part + ((size_t)chunk * 32 + b) * 32 * 256;
#pragma unroll
  for (int m = 0; m < 32; ++m) pp[m * 256 + c] = acc[m];  // coalesced
}

// ---------------------------------------------------------------------------
// Stage 1b: reduce 8 partials + bias -> wp[b][c][m] (m contiguous for stage 2).
// ---------------------------------------------------------------------------
__global__ __launch_bounds__(256) void stage1_reduce(
    const float* __restrict__ part, const float* __restrict__ bias,
    float* __restrict__ wp) {
  const int idx = blockIdx.x * 256 + threadIdx.x;  // (b, m, c), c innermost
  const int c = idx & 255;
  const int m = (idx >> 8) & 31;
  const int b = idx >> 13;
  float s = bias[c];
#pragma unroll
  for (int k = 0; k < 8; ++k)
    s += part[(((size_t)k * 32 + b) * 32 + m) * 256 + c];  // coalesced
  wp[((size_t)b * 256 + c) * 32 + m] = s;
}

// ---------------------------------------------------------------------------
// Stage 2 (R-new): occupancy-recovered fused attention.
// R-old ran 512 blocks x 256 thr = 2 waves/SIMD -> latency-bound at 22% HBM,
// 36% VALU, 21% occupancy. Fix: split the 256-channel reduction across 4
// thread groups (64 channels each) inside a 512-thread block covering 128
// pixels. Grid = 32 b x 32 tiles = 1024 blocks = 4 blocks/CU = 32 waves/CU.
// Partials combined via a 2-buffer LDS tree ([m][px] layout: lane=px ->
// conflict-free b32 ops; 32 KB/block -> 128 KB/CU at 4 blocks, under 160 KB).
// __launch_bounds__(512,8) pins VGPR<=64 so all 4 blocks are resident.
// Global traffic unchanged (optimal 272 MB): images read once, outputs
// written once, wp stays SGPR-uniform per block.
// ---------------------------------------------------------------------------
__global__ __launch_bounds__(512, 8) void attention_fused(
    const float* __restrict__ images, const float* __restrict__ wp,
    const int* __restrict__ maskn, float* __restrict__ out_w,
    float* __restrict__ out_a) {
  __shared__ float redA[32][128];
  __shared__ float redB[32][128];
  const int t = threadIdx.x;
  const int px = t & 127;          // pixel within tile
  const int g = t >> 7;            // channel group 0..3
  const int b = blockIdx.x >> 5;   // batch
  const int p = ((blockIdx.x & 31) << 7) + px;  // pixel 0..4095
  const int cbase = g << 6;        // this group's first channel
  const float* img = images + ((size_t)b * NC_ + cbase) * HW_ + p;
  const float* wpb = wp + (size_t)b * NC_ * MW_;

  // partial scores over this group's 64 channels
  float s[32];
#pragma unroll
  for (int m = 0; m < 32; ++m) s[m] = 0.f;

  float cur[8];
#pragma unroll
  for (int j = 0; j < 8; ++j)
    cur[j] = __builtin_nontemporal_load(img + ((size_t)j << 12));

#pragma unroll 1
  for (int cc = 0; cc < 64; cc += 8) {
    float nxt[8];
    if (cc + 8 < 64) {
#pragma unroll
      for (int j = 0; j < 8; ++j)
        nxt[j] = __builtin_nontemporal_load(img + ((size_t)(cc + 8 + j) << 12));
    }
#pragma unroll
    for (int j = 0; j < 8; ++j) {
      const int c = cbase + cc + j;
#pragma unroll
      for (int m = 0; m < 32; ++m)
        s[m] = fmaf(cur[j], wpb[(c << 5) + m], s[m]);  // SGPR operand
    }
#pragma unroll
    for (int j = 0; j < 8; ++j) cur[j] = nxt[j];  // dead on last iter
  }

  // LDS tree-reduce of the 4 partial score sets: (g2,g3) -> (g0,g1) -> g0
  if (g == 2) {
#pragma unroll
    for (int m = 0; m < 32; ++m) redA[m][px] = s[m];
  } else if (g == 3) {
#pragma unroll
    for (int m = 0; m < 32; ++m) redB[m][px] = s[m];
  }
  __syncthreads();
  if (g == 0) {
#pragma unroll
    for (int m = 0; m < 32; ++m) s[m] += redA[m][px];
  } else if (g == 1) {
#pragma unroll
    for (int m = 0; m < 32; ++m) s[m] += redB[m][px];
  }
  __syncthreads();
  if (g == 1) {
#pragma unroll
    for (int m = 0; m < 32; ++m) redA[m][px] = s[m];
  }
  __syncthreads();

  if (g == 0) {
    // mask bits (wave-uniform)
    unsigned mbits = 0;
#pragma unroll
    for (int m = 0; m < 32; ++m)
      mbits |= (maskn[(b << 5) + m] != 0 ? 1u : 0u) << m;

    // softmax over m (scale 1/sqrt(256) = 0.0625); masked -> exactly 0
    float mx = NEG_BIG;
#pragma unroll
    for (int m = 0; m < 32; ++m) {
      s[m] = (s[m] + redA[m][px]) * 0.0625f;
      if (!((mbits >> m) & 1u)) mx = fmaxf(mx, s[m]);
    }
    float sum = 0.f;
#pragma unroll
    for (int m = 0; m < 32; ++m) {
      const float ev = ((mbits >> m) & 1u) ? 0.f : __expf(s[m] - mx);
      s[m] = ev;
      sum += ev;
    }
    const float inv = 1.f / sum;
#pragma unroll
    for (int m = 0; m < 32; ++m) {
      const float a = s[m] * inv;
      redA[m][px] = a;  // broadcast to all groups
      __builtin_nontemporal_store(a, out_a + ((size_t)((b << 5) + m) << 12) + p);
    }
  }
  __syncthreads();

  // weighted words: each group writes its own 64 channels
  float a[32];
#pragma unroll
  for (int m = 0; m < 32; ++m) a[m] = redA[m][px];

#pragma unroll 1
  for (int cc = 0; cc < 64; cc += 8) {
#pragma unroll
    for (int jc = 0; jc < 8; ++jc) {
      const int c = cbase + cc + jc;
      float o = 0.f;
#pragma unroll
      for (int m = 0; m < 32; ++m)
        o = fmaf(wpb[(c << 5) + m], a[m], o);  // SGPR operand
      __builtin_nontemporal_store(o, out_w + ((size_t)((b << 8) + c) << 12) + p);
    }
  }
}

// ---------------------------------------------------------------------------
extern "C" void kernel_launch(void* const* d_in, const int* in_sizes, int n_in,
                              void* d_out, int out_size, void* d_ws, size_t ws_size,
                              hipStream_t stream) {
  const float* images = (const float*)d_in[0];
  const float* words  = (const float*)d_in[1];
  const void*  mask   = d_in[2];
  const float* W      = (const float*)d_in[3];
  const float* bias   = (const float*)d_in[4];

  float* ws     = (float*)d_ws;
  float* part   = ws + PART_OFF;
  float* wp     = ws + WP_OFF;
  float* WT     = ws + WT_OFF;
  float* wordsT = ws + WORDST_OFF;
  int*   maskn  = (int*)(ws + MASK_OFF);

  float* out_w = (float*)d_out;
  float* out_a = out_w + (size_t)B_ * NC_ * HW_;

  prep_kernel<<<961, 256, 0, stream>>>(W, words, mask, WT, wordsT, maskn);
  stage1_partial<<<256, 256, 0, stream>>>(wordsT, WT, part);
  stage1_reduce<<<1024, 256, 0, stream>>>(part, bias, wp);
  attention_fused<<<1024, 512, 0, stream>>>(images, wp, maskn, out_w, out_a);
}

// Round 2
// 508.782 us; speedup vs baseline: 1.0719x; 1.0719x over previous
//
#include <hip/hip_runtime.h>
#include <math.h>

// Problem shape (fixed by reference setup_inputs):
//   images [32][256][64][64] fp32, words [32][32][768] fp32, mask [32][32] bool,
//   W [256][768] fp32, b [256] fp32
//   out0 weighted_words [32][256][64][64], out1 attn_out [32][32][64][64], fp32 concat.
#define B_   32
#define NC_  256
#define HW_  4096
#define MW_  32
#define E_   768
#define NEG_BIG -3.0e38f

// Workspace layout (float offsets). Total ~13.4 MB.
#define PART_OFF   0          // partial GEMM: 8 chunks * 32b * 32m * 256c = 2097152 floats
#define WP_OFF     2097152    // words_p [b][c][m]: 262144 floats
#define WT_OFF     2359296    // W transposed [e][c]: 196608 floats
#define WORDST_OFF 2555904    // words transposed [b][e][m]: 786432 floats
#define MASK_OFF   3342336    // normalized mask: 1024 ints

// ---------------------------------------------------------------------------
// Prep: tiled transposes (W 256x768 -> WT 768x256; words[b] 32x768 ->
// wordsT[b] 768x32) + mask normalization.
// Blocks 0..191: W transpose. 192..959: words transpose. 960: mask.
// ---------------------------------------------------------------------------
__global__ __launch_bounds__(256) void prep_kernel(
    const float* __restrict__ W, const float* __restrict__ words,
    const void* __restrict__ mask_raw,
    float* __restrict__ WT, float* __restrict__ wordsT,
    int* __restrict__ maskn) {
  const int tid = threadIdx.x;
  const int tx = tid & 31, ty = tid >> 5;
  if (blockIdx.x < 192) {
    // W: 32x32 tile transpose; tiles: 8 (c) x 24 (e)
    __shared__ float t[32][33];
    const int tc = blockIdx.x / 24, te = blockIdx.x % 24;
    const int c0 = tc * 32, e0 = te * 32;
#pragma unroll
    for (int k = 0; k < 4; ++k) {
      const int r = ty + 8 * k;
      t[r][tx] = W[(c0 + r) * E_ + e0 + tx];  // coalesced over tx
    }
    __syncthreads();
#pragma unroll
    for (int k = 0; k < 4; ++k) {
      const int r = ty + 8 * k;
      WT[(e0 + r) * NC_ + c0 + tx] = t[tx][r];  // coalesced over tx
    }
  } else if (blockIdx.x < 960) {
    // words[b]: 32(m) x 768(e) -> wordsT[b]: 768(e) x 32(m). tiles: 32 b x 24 e
    __shared__ float t[32][33];
    const int idx = blockIdx.x - 192;
    const int b = idx / 24, te = idx % 24;
    const int e0 = te * 32;
    const float* wsrc = words + (size_t)b * MW_ * E_;
    float* wdst = wordsT + (size_t)b * E_ * MW_;
#pragma unroll
    for (int k = 0; k < 4; ++k) {
      const int m = ty + 8 * k;
      t[m][tx] = wsrc[m * E_ + e0 + tx];        // coalesced over tx (e)
    }
    __syncthreads();
#pragma unroll
    for (int k = 0; k < 4; ++k) {
      const int e = ty + 8 * k;
      wdst[(e0 + e) * MW_ + tx] = t[tx][e];     // coalesced over tx (m)
    }
  } else {
    // Mask layout detection + normalize to int[1024].
    __shared__ int is_word;  // 1 if 4-byte-per-element layout (int32 or fp32)
    if (tid == 0) is_word = 1;
    __syncthreads();
    const int* mi = (const int*)mask_raw;
    const int v = mi[tid];  // reads only first 1024 bytes: safe for any layout
    if (v != 0 && v != 1 && v != 0x3F800000) is_word = 0;
    __syncthreads();
    if (is_word) {
#pragma unroll
      for (int j = 0; j < 4; ++j) { const int i = j * 256 + tid; maskn[i] = (mi[i] != 0); }
    } else {
      const unsigned char* mb = (const unsigned char*)mask_raw;
#pragma unroll
      for (int j = 0; j < 4; ++j) { const int i = j * 256 + tid; maskn[i] = (mb[i] != 0); }
    }
  }
}

// ---------------------------------------------------------------------------
// Stage 1a: words_p partials. Block = (batch, e-chunk of 96). lane = c.
// WT[e][c] coalesced vector load; wordsT[b][e][0..31] is wave-uniform AND
// contiguous -> 2x s_load_dwordx16 per e.
// ---------------------------------------------------------------------------
__global__ __launch_bounds__(256) void stage1_partial(
    const float* __restrict__ wordsT, const float* __restrict__ WT,
    float* __restrict__ part) {
  const int c = threadIdx.x;
  const int b = blockIdx.x >> 3;
  const int chunk = blockIdx.x & 7;
  const int e0 = chunk * 96;
  const float* wt = wordsT + (size_t)b * E_ * MW_;
  float acc[32];
#pragma unroll
  for (int m = 0; m < 32; ++m) acc[m] = 0.f;
#pragma unroll 2
  for (int e = e0; e < e0 + 96; ++e) {
    const float wv = WT[(size_t)e * NC_ + c];   // coalesced over lanes
    const float* wr = wt + e * MW_;             // uniform, contiguous
#pragma unroll
    for (int m = 0; m < 32; ++m) acc[m] = fmaf(wv, wr[m], acc[m]);
  }
  float* pp = part + ((size_t)chunk * 32 + b) * 32 * 256;
#pragma unroll
  for (int m = 0; m < 32; ++m) pp[m * 256 + c] = acc[m];  // coalesced
}

// ---------------------------------------------------------------------------
// Stage 1b: reduce 8 partials + bias -> wp[b][c][m] (m contiguous for stage 2).
// ---------------------------------------------------------------------------
__global__ __launch_bounds__(256) void stage1_reduce(
    const float* __restrict__ part, const float* __restrict__ bias,
    float* __restrict__ wp) {
  const int idx = blockIdx.x * 256 + threadIdx.x;  // (b, m, c), c innermost
  const int c = idx & 255;
  const int m = (idx >> 8) & 31;
  const int b = idx >> 13;
  float s = bias[c];
#pragma unroll
  for (int k = 0; k < 8; ++k)
    s += part[(((size_t)k * 32 + b) * 32 + m) * 256 + c];  // coalesced
  wp[((size_t)b * 256 + c) * 32 + m] = s;
}

// ---------------------------------------------------------------------------
// Stage 2 (R2): occupancy-recovered fused attention, spill-free.
// R0: 1 px/thread, 2 waves/SIMD -> latency-bound (36% VALU, 128 us).
// R1: 4-way c-split at __launch_bounds__(512,8) -> VGPR capped at 64 ->
//     s[32] spilled to scratch (VGPR_Count=32, WRITE_SIZE +174 MB, 16% VALU,
//     334 us). Structure was right; register budget was wrong.
// R2: same 4-way c-split (64 channels/group) but 256-thread blocks
//     (64 px x 4 groups) and __launch_bounds__(256,5) -> VGPR cap 102,
//     live set ~75 fits with margin. Grid = 32 b x 64 tiles = 2048 blocks;
//     8192 waves available; actual residency VGPR-limited at ~5-6 blocks/CU
//     = 20-24 waves/CU, ~3x R0. LDS tree-reduce: 2 x [32][64] = 16 KB/block
//     ([m][px], lane=px -> 2 lanes/bank = free). Global traffic stays at the
//     optimal 272 MB: images read once, outputs written once, wp SGPR-uniform.
// ---------------------------------------------------------------------------
__global__ __launch_bounds__(256, 5) void attention_fused(
    const float* __restrict__ images, const float* __restrict__ wp,
    const int* __restrict__ maskn, float* __restrict__ out_w,
    float* __restrict__ out_a) {
  __shared__ float redA[32][64];
  __shared__ float redB[32][64];
  const int t = threadIdx.x;
  const int px = t & 63;           // pixel within tile (== lane)
  const int g = t >> 6;            // channel group 0..3 (== wave)
  const int b = blockIdx.x >> 6;   // batch
  const int p = ((blockIdx.x & 63) << 6) + px;  // pixel 0..4095
  const int cbase = g << 6;        // this group's first channel
  const float* img = images + ((size_t)b * NC_ + cbase) * HW_ + p;
  const float* wpb = wp + (size_t)b * NC_ * MW_;

  // partial scores over this group's 64 channels
  float s[32];
#pragma unroll
  for (int m = 0; m < 32; ++m) s[m] = 0.f;

  float cur[8];
#pragma unroll
  for (int j = 0; j < 8; ++j)
    cur[j] = __builtin_nontemporal_load(img + ((size_t)j << 12));

#pragma unroll 1
  for (int cc = 0; cc < 64; cc += 8) {
    float nxt[8];
    if (cc + 8 < 64) {
#pragma unroll
      for (int j = 0; j < 8; ++j)
        nxt[j] = __builtin_nontemporal_load(img + ((size_t)(cc + 8 + j) << 12));
    }
#pragma unroll
    for (int j = 0; j < 8; ++j) {
      const int c = cbase + cc + j;
#pragma unroll
      for (int m = 0; m < 32; ++m)
        s[m] = fmaf(cur[j], wpb[(c << 5) + m], s[m]);  // SGPR operand
    }
#pragma unroll
    for (int j = 0; j < 8; ++j) cur[j] = nxt[j];  // dead on last iter
  }

  // LDS tree-reduce of the 4 partial score sets: (g2,g3) -> (g0,g1) -> g0
  if (g == 2) {
#pragma unroll
    for (int m = 0; m < 32; ++m) redA[m][px] = s[m];
  } else if (g == 3) {
#pragma unroll
    for (int m = 0; m < 32; ++m) redB[m][px] = s[m];
  }
  __syncthreads();
  if (g == 0) {
#pragma unroll
    for (int m = 0; m < 32; ++m) s[m] += redA[m][px];
  } else if (g == 1) {
#pragma unroll
    for (int m = 0; m < 32; ++m) s[m] += redB[m][px];
  }
  __syncthreads();
  if (g == 1) {
#pragma unroll
    for (int m = 0; m < 32; ++m) redA[m][px] = s[m];
  }
  __syncthreads();

  if (g == 0) {
    // mask bits (wave-uniform)
    unsigned mbits = 0;
#pragma unroll
    for (int m = 0; m < 32; ++m)
      mbits |= (maskn[(b << 5) + m] != 0 ? 1u : 0u) << m;

    // softmax over m (scale 1/sqrt(256) = 0.0625); masked -> exactly 0
    float mx = NEG_BIG;
#pragma unroll
    for (int m = 0; m < 32; ++m) {
      s[m] = (s[m] + redA[m][px]) * 0.0625f;
      if (!((mbits >> m) & 1u)) mx = fmaxf(mx, s[m]);
    }
    float sum = 0.f;
#pragma unroll
    for (int m = 0; m < 32; ++m) {
      const float ev = ((mbits >> m) & 1u) ? 0.f : __expf(s[m] - mx);
      s[m] = ev;
      sum += ev;
    }
    const float inv = 1.f / sum;
#pragma unroll
    for (int m = 0; m < 32; ++m) {
      const float a = s[m] * inv;
      redA[m][px] = a;  // broadcast to all groups
      __builtin_nontemporal_store(a, out_a + ((size_t)((b << 5) + m) << 12) + p);
    }
  }
  __syncthreads();

  // weighted words: each group writes its own 64 channels
  float a[32];
#pragma unroll
  for (int m = 0; m < 32; ++m) a[m] = redA[m][px];

#pragma unroll 1
  for (int cc = 0; cc < 64; cc += 8) {
#pragma unroll
    for (int jc = 0; jc < 8; ++jc) {
      const int c = cbase + cc + jc;
      float o = 0.f;
#pragma unroll
      for (int m = 0; m < 32; ++m)
        o = fmaf(wpb[(c << 5) + m], a[m], o);  // SGPR operand
      __builtin_nontemporal_store(o, out_w + ((size_t)((b << 8) + c) << 12) + p);
    }
  }
}

// ---------------------------------------------------------------------------
extern "C" void kernel_launch(void* const* d_in, const int* in_sizes, int n_in,
                              void* d_out, int out_size, void* d_ws, size_t ws_size,
                              hipStream_t stream) {
  const float* images = (const float*)d_in[0];
  const float* words  = (const float*)d_in[1];
  const void*  mask   = d_in[2];
  const float* W      = (const float*)d_in[3];
  const float* bias   = (const float*)d_in[4];

  float* ws     = (float*)d_ws;
  float* part   = ws + PART_OFF;
  float* wp     = ws + WP_OFF;
  float* WT     = ws + WT_OFF;
  float* wordsT = ws + WORDST_OFF;
  int*   maskn  = (int*)(ws + MASK_OFF);

  float* out_w = (float*)d_out;
  float* out_a = out_w + (size_t)B_ * NC_ * HW_;

  prep_kernel<<<961, 256, 0, stream>>>(W, words, mask, WT, wordsT, maskn);
  stage1_partial<<<256, 256, 0, stream>>>(wordsT, WT, part);
  stage1_reduce<<<1024, 256, 0, stream>>>(part, bias, wp);
  attention_fused<<<2048, 256, 0, stream>>>(images, wp, maskn, out_w, out_a);
}

// Round 3
// 479.556 us; speedup vs baseline: 1.1372x; 1.0609x over previous
//
#include <hip/hip_runtime.h>
#include <math.h>

// Problem shape (fixed by reference setup_inputs):
//   images [32][256][64][64] fp32, words [32][32][768] fp32, mask [32][32] bool,
//   W [256][768] fp32, b [256] fp32
//   out0 weighted_words [32][256][64][64], out1 attn_out [32][32][64][64], fp32 concat.
#define B_   32
#define NC_  256
#define HW_  4096
#define MW_  32
#define E_   768
#define NEG_BIG -3.0e38f

// Workspace layout (float offsets). Total ~13.4 MB.
#define PART_OFF   0          // partial GEMM: 8 chunks * 32b * 32m * 256c = 2097152 floats
#define WP_OFF     2097152    // words_p [b][c][m]: 262144 floats
#define WT_OFF     2359296    // W transposed [e][c]: 196608 floats
#define WORDST_OFF 2555904    // words transposed [b][e][m]: 786432 floats
#define MASK_OFF   3342336    // normalized mask: 1024 ints

// ---------------------------------------------------------------------------
// Prep: tiled transposes (W 256x768 -> WT 768x256; words[b] 32x768 ->
// wordsT[b] 768x32) + mask normalization.
// Blocks 0..191: W transpose. 192..959: words transpose. 960: mask.
// ---------------------------------------------------------------------------
__global__ __launch_bounds__(256) void prep_kernel(
    const float* __restrict__ W, const float* __restrict__ words,
    const void* __restrict__ mask_raw,
    float* __restrict__ WT, float* __restrict__ wordsT,
    int* __restrict__ maskn) {
  const int tid = threadIdx.x;
  const int tx = tid & 31, ty = tid >> 5;
  if (blockIdx.x < 192) {
    // W: 32x32 tile transpose; tiles: 8 (c) x 24 (e)
    __shared__ float t[32][33];
    const int tc = blockIdx.x / 24, te = blockIdx.x % 24;
    const int c0 = tc * 32, e0 = te * 32;
#pragma unroll
    for (int k = 0; k < 4; ++k) {
      const int r = ty + 8 * k;
      t[r][tx] = W[(c0 + r) * E_ + e0 + tx];  // coalesced over tx
    }
    __syncthreads();
#pragma unroll
    for (int k = 0; k < 4; ++k) {
      const int r = ty + 8 * k;
      WT[(e0 + r) * NC_ + c0 + tx] = t[tx][r];  // coalesced over tx
    }
  } else if (blockIdx.x < 960) {
    // words[b]: 32(m) x 768(e) -> wordsT[b]: 768(e) x 32(m). tiles: 32 b x 24 e
    __shared__ float t[32][33];
    const int idx = blockIdx.x - 192;
    const int b = idx / 24, te = idx % 24;
    const int e0 = te * 32;
    const float* wsrc = words + (size_t)b * MW_ * E_;
    float* wdst = wordsT + (size_t)b * E_ * MW_;
#pragma unroll
    for (int k = 0; k < 4; ++k) {
      const int m = ty + 8 * k;
      t[m][tx] = wsrc[m * E_ + e0 + tx];        // coalesced over tx (e)
    }
    __syncthreads();
#pragma unroll
    for (int k = 0; k < 4; ++k) {
      const int e = ty + 8 * k;
      wdst[(e0 + e) * MW_ + tx] = t[tx][e];     // coalesced over tx (m)
    }
  } else {
    // Mask layout detection + normalize to int[1024].
    __shared__ int is_word;  // 1 if 4-byte-per-element layout (int32 or fp32)
    if (tid == 0) is_word = 1;
    __syncthreads();
    const int* mi = (const int*)mask_raw;
    const int v = mi[tid];  // reads only first 1024 bytes: safe for any layout
    if (v != 0 && v != 1 && v != 0x3F800000) is_word = 0;
    __syncthreads();
    if (is_word) {
#pragma unroll
      for (int j = 0; j < 4; ++j) { const int i = j * 256 + tid; maskn[i] = (mi[i] != 0); }
    } else {
      const unsigned char* mb = (const unsigned char*)mask_raw;
#pragma unroll
      for (int j = 0; j < 4; ++j) { const int i = j * 256 + tid; maskn[i] = (mb[i] != 0); }
    }
  }
}

// ---------------------------------------------------------------------------
// Stage 1a: words_p partials. Block = (batch, e-chunk of 96). lane = c.
// ---------------------------------------------------------------------------
__global__ __launch_bounds__(256) void stage1_partial(
    const float* __restrict__ wordsT, const float* __restrict__ WT,
    float* __restrict__ part) {
  const int c = threadIdx.x;
  const int b = blockIdx.x >> 3;
  const int chunk = blockIdx.x & 7;
  const int e0 = chunk * 96;
  const float* wt = wordsT + (size_t)b * E_ * MW_;
  float acc[32];
#pragma unroll
  for (int m = 0; m < 32; ++m) acc[m] = 0.f;
#pragma unroll 2
  for (int e = e0; e < e0 + 96; ++e) {
    const float wv = WT[(size_t)e * NC_ + c];   // coalesced over lanes
    const float* wr = wt + e * MW_;             // uniform, contiguous
#pragma unroll
    for (int m = 0; m < 32; ++m) acc[m] = fmaf(wv, wr[m], acc[m]);
  }
  float* pp = part + ((size_t)chunk * 32 + b) * 32 * 256;
#pragma unroll
  for (int m = 0; m < 32; ++m) pp[m * 256 + c] = acc[m];  // coalesced
}

// ---------------------------------------------------------------------------
// Stage 1b: reduce 8 partials + bias -> wp[b][c][m] (m contiguous for stage 2).
// ---------------------------------------------------------------------------
__global__ __launch_bounds__(256) void stage1_reduce(
    const float* __restrict__ part, const float* __restrict__ bias,
    float* __restrict__ wp) {
  const int idx = blockIdx.x * 256 + threadIdx.x;  // (b, m, c), c innermost
  const int c = idx & 255;
  const int m = (idx >> 8) & 31;
  const int b = idx >> 13;
  float s = bias[c];
#pragma unroll
  for (int k = 0; k < 8; ++k)
    s += part[(((size_t)k * 32 + b) * 32 + m) * 256 + c];  // coalesced
  wp[((size_t)b * 256 + c) * 32 + m] = s;
}

// ---------------------------------------------------------------------------
// Stage 2 (R3): spill-free 4-way channel-split fused attention.
// History:
//   R0: 1 px/thread, 512 blocks -> 2 waves/SIMD, latency-bound, 128 us.
//   R1: c-split @ __launch_bounds__(512,8): VGPR capped 64 -> scratch spill
//       to HBM (WRITE +174MB), 334 us.
//   R2: c-split @ __launch_bounds__(256,5): allocator squeezed to VGPR=48
//       (< ~58 live set) -> L2-resident scratch spills in the inner loop
//       (WRITE exactly = outputs, VALU 17%, per-wave issue 4x worse), 304 us.
// R3 fixes the register budget instead of the structure:
//   - __launch_bounds__(256,4): VGPR cap 128, live set ~80 -> ZERO spills.
//     Residency ~5-6 blocks/CU (20-24 waves/CU), 3x R0's wave count.
//   - 16-deep img prefetch (fits now): covers ~900cy HBM latency per
//     1024-cy FMA chunk.
//   - batch-minor grid (b = blockIdx&31): CU-resident blocks (stride 256 in
//     blockIdx) share one batch -> wp scalar-cache working set 8x smaller.
//   - 2 barriers, softmax redundantly in ALL groups (uniform flow, no
//     serialized g0 section); out_a stored by g0 only.
// Global traffic stays optimal (~272 MB): images once, outputs once.
// ---------------------------------------------------------------------------
__global__ __launch_bounds__(256, 4) void attention_fused(
    const float* __restrict__ images, const float* __restrict__ wp,
    const int* __restrict__ maskn, float* __restrict__ out_w,
    float* __restrict__ out_a) {
  __shared__ float redA[32][64];
  __shared__ float redB[32][64];
  const int t = threadIdx.x;
  const int px = t & 63;           // pixel within tile (== lane)
  const int g = t >> 6;            // channel group 0..3 (== wave)
  const int b = blockIdx.x & 31;   // batch-minor: CU-residents share batch
  const int p = ((blockIdx.x >> 5) << 6) + px;  // pixel 0..4095
  const int cbase = g << 6;        // this group's first channel
  const float* img = images + ((size_t)b * NC_ + cbase) * HW_ + p;
  const float* wpb = wp + (size_t)b * NC_ * MW_;

  // partial scores over this group's 64 channels
  float s[32];
#pragma unroll
  for (int m = 0; m < 32; ++m) s[m] = 0.f;

  float cur[16];
#pragma unroll
  for (int j = 0; j < 16; ++j)
    cur[j] = __builtin_nontemporal_load(img + ((size_t)j << 12));

#pragma unroll 1
  for (int cc = 0; cc < 64; cc += 16) {
    float nxt[16];
    if (cc + 16 < 64) {
#pragma unroll
      for (int j = 0; j < 16; ++j)
        nxt[j] = __builtin_nontemporal_load(img + ((size_t)(cc + 16 + j) << 12));
    }
#pragma unroll
    for (int j = 0; j < 16; ++j) {
      const int c = cbase + cc + j;
#pragma unroll
      for (int m = 0; m < 32; ++m)
        s[m] = fmaf(cur[j], wpb[(c << 5) + m], s[m]);  // SGPR operand
    }
#pragma unroll
    for (int j = 0; j < 16; ++j) cur[j] = nxt[j];  // dead on last iter
  }

  // 2-barrier tree-reduce: (g2->redA, g3->redB); (g0 += redA -> redA,
  // g1 += redB -> redB); then every group reads redA+redB = full sum.
  if (g == 2) {
#pragma unroll
    for (int m = 0; m < 32; ++m) redA[m][px] = s[m];
  } else if (g == 3) {
#pragma unroll
    for (int m = 0; m < 32; ++m) redB[m][px] = s[m];
  }
  __syncthreads();
  if (g == 0) {
#pragma unroll
    for (int m = 0; m < 32; ++m) { s[m] += redA[m][px]; redA[m][px] = s[m]; }
  } else if (g == 1) {
#pragma unroll
    for (int m = 0; m < 32; ++m) { s[m] += redB[m][px]; redB[m][px] = s[m]; }
  }
  __syncthreads();

  // mask bits (wave-uniform)
  unsigned mbits = 0;
#pragma unroll
  for (int m = 0; m < 32; ++m)
    mbits |= (maskn[(b << 5) + m] != 0 ? 1u : 0u) << m;

  // softmax over m (scale 1/sqrt(256) = 0.0625); all groups compute it
  // redundantly (identical ops -> identical results); masked -> exactly 0
  float mx = NEG_BIG;
#pragma unroll
  for (int m = 0; m < 32; ++m) {
    s[m] = (redA[m][px] + redB[m][px]) * 0.0625f;
    if (!((mbits >> m) & 1u)) mx = fmaxf(mx, s[m]);
  }
  float sum = 0.f;
#pragma unroll
  for (int m = 0; m < 32; ++m) {
    const float ev = ((mbits >> m) & 1u) ? 0.f : __expf(s[m] - mx);
    s[m] = ev;
    sum += ev;
  }
  const float inv = 1.f / sum;
#pragma unroll
  for (int m = 0; m < 32; ++m) s[m] *= inv;

  if (g == 0) {
#pragma unroll
    for (int m = 0; m < 32; ++m)
      __builtin_nontemporal_store(s[m], out_a + ((size_t)((b << 5) + m) << 12) + p);
  }

  // weighted words: each group writes its own 64 channels
#pragma unroll 1
  for (int cc = 0; cc < 64; cc += 8) {
#pragma unroll
    for (int jc = 0; jc < 8; ++jc) {
      const int c = cbase + cc + jc;
      float o = 0.f;
#pragma unroll
      for (int m = 0; m < 32; ++m)
        o = fmaf(wpb[(c << 5) + m], s[m], o);  // SGPR operand
      __builtin_nontemporal_store(o, out_w + ((size_t)((b << 8) + c) << 12) + p);
    }
  }
}

// ---------------------------------------------------------------------------
extern "C" void kernel_launch(void* const* d_in, const int* in_sizes, int n_in,
                              void* d_out, int out_size, void* d_ws, size_t ws_size,
                              hipStream_t stream) {
  const float* images = (const float*)d_in[0];
  const float* words  = (const float*)d_in[1];
  const void*  mask   = d_in[2];
  const float* W      = (const float*)d_in[3];
  const float* bias   = (const float*)d_in[4];

  float* ws     = (float*)d_ws;
  float* part   = ws + PART_OFF;
  float* wp     = ws + WP_OFF;
  float* WT     = ws + WT_OFF;
  float* wordsT = ws + WORDST_OFF;
  int*   maskn  = (int*)(ws + MASK_OFF);

  float* out_w = (float*)d_out;
  float* out_a = out_w + (size_t)B_ * NC_ * HW_;

  prep_kernel<<<961, 256, 0, stream>>>(W, words, mask, WT, wordsT, maskn);
  stage1_partial<<<256, 256, 0, stream>>>(wordsT, WT, part);
  stage1_reduce<<<1024, 256, 0, stream>>>(part, bias, wp);
  attention_fused<<<2048, 256, 0, stream>>>(images, wp, maskn, out_w, out_a);
}

// Round 4
// 316.303 us; speedup vs baseline: 1.7242x; 1.5161x over previous
//
#include <hip/hip_runtime.h>
#include <math.h>

// Problem shape (fixed by reference setup_inputs):
//   images [32][256][64][64] fp32, words [32][32][768] fp32, mask [32][32] bool,
//   W [256][768] fp32, b [256] fp32
//   out0 weighted_words [32][256][64][64], out1 attn_out [32][32][64][64], fp32 concat.
#define B_   32
#define NC_  256
#define HW_  4096
#define MW_  32
#define E_   768
#define NEG_BIG -3.0e38f

// Workspace layout (float offsets). Total ~13.4 MB.
#define PART_OFF   0          // partial GEMM: 8 chunks * 32b * 32m * 256c = 2097152 floats
#define WP_OFF     2097152    // words_p [b][c][m]: 262144 floats
#define WT_OFF     2359296    // W transposed [e][c]: 196608 floats
#define WORDST_OFF 2555904    // words transposed [b][e][m]: 786432 floats
#define MASK_OFF   3342336    // normalized mask: 1024 ints

// ---------------------------------------------------------------------------
// Prep: tiled transposes (W 256x768 -> WT 768x256; words[b] 32x768 ->
// wordsT[b] 768x32) + mask normalization.
// Blocks 0..191: W transpose. 192..959: words transpose. 960: mask.
// ---------------------------------------------------------------------------
__global__ __launch_bounds__(256) void prep_kernel(
    const float* __restrict__ W, const float* __restrict__ words,
    const void* __restrict__ mask_raw,
    float* __restrict__ WT, float* __restrict__ wordsT,
    int* __restrict__ maskn) {
  const int tid = threadIdx.x;
  const int tx = tid & 31, ty = tid >> 5;
  if (blockIdx.x < 192) {
    // W: 32x32 tile transpose; tiles: 8 (c) x 24 (e)
    __shared__ float t[32][33];
    const int tc = blockIdx.x / 24, te = blockIdx.x % 24;
    const int c0 = tc * 32, e0 = te * 32;
#pragma unroll
    for (int k = 0; k < 4; ++k) {
      const int r = ty + 8 * k;
      t[r][tx] = W[(c0 + r) * E_ + e0 + tx];  // coalesced over tx
    }
    __syncthreads();
#pragma unroll
    for (int k = 0; k < 4; ++k) {
      const int r = ty + 8 * k;
      WT[(e0 + r) * NC_ + c0 + tx] = t[tx][r];  // coalesced over tx
    }
  } else if (blockIdx.x < 960) {
    // words[b]: 32(m) x 768(e) -> wordsT[b]: 768(e) x 32(m). tiles: 32 b x 24 e
    __shared__ float t[32][33];
    const int idx = blockIdx.x - 192;
    const int b = idx / 24, te = idx % 24;
    const int e0 = te * 32;
    const float* wsrc = words + (size_t)b * MW_ * E_;
    float* wdst = wordsT + (size_t)b * E_ * MW_;
#pragma unroll
    for (int k = 0; k < 4; ++k) {
      const int m = ty + 8 * k;
      t[m][tx] = wsrc[m * E_ + e0 + tx];        // coalesced over tx (e)
    }
    __syncthreads();
#pragma unroll
    for (int k = 0; k < 4; ++k) {
      const int e = ty + 8 * k;
      wdst[(e0 + e) * MW_ + tx] = t[tx][e];     // coalesced over tx (m)
    }
  } else {
    // Mask layout detection + normalize to int[1024].
    __shared__ int is_word;  // 1 if 4-byte-per-element layout (int32 or fp32)
    if (tid == 0) is_word = 1;
    __syncthreads();
    const int* mi = (const int*)mask_raw;
    const int v = mi[tid];  // reads only first 1024 bytes: safe for any layout
    if (v != 0 && v != 1 && v != 0x3F800000) is_word = 0;
    __syncthreads();
    if (is_word) {
#pragma unroll
      for (int j = 0; j < 4; ++j) { const int i = j * 256 + tid; maskn[i] = (mi[i] != 0); }
    } else {
      const unsigned char* mb = (const unsigned char*)mask_raw;
#pragma unroll
      for (int j = 0; j < 4; ++j) { const int i = j * 256 + tid; maskn[i] = (mb[i] != 0); }
    }
  }
}

// ---------------------------------------------------------------------------
// Stage 1a: words_p partials. Block = (batch, e-chunk of 96). lane = c.
// ---------------------------------------------------------------------------
__global__ __launch_bounds__(256) void stage1_partial(
    const float* __restrict__ wordsT, const float* __restrict__ WT,
    float* __restrict__ part) {
  const int c = threadIdx.x;
  const int b = blockIdx.x >> 3;
  const int chunk = blockIdx.x & 7;
  const int e0 = chunk * 96;
  const float* wt = wordsT + (size_t)b * E_ * MW_;
  float acc[32];
#pragma unroll
  for (int m = 0; m < 32; ++m) acc[m] = 0.f;
#pragma unroll 2
  for (int e = e0; e < e0 + 96; ++e) {
    const float wv = WT[(size_t)e * NC_ + c];   // coalesced over lanes
    const float* wr = wt + e * MW_;             // uniform, contiguous
#pragma unroll
    for (int m = 0; m < 32; ++m) acc[m] = fmaf(wv, wr[m], acc[m]);
  }
  float* pp = part + ((size_t)chunk * 32 + b) * 32 * 256;
#pragma unroll
  for (int m = 0; m < 32; ++m) pp[m * 256 + c] = acc[m];  // coalesced
}

// ---------------------------------------------------------------------------
// Stage 1b: reduce 8 partials + bias -> wp[b][c][m] (m contiguous for stage 2).
// ---------------------------------------------------------------------------
__global__ __launch_bounds__(256) void stage1_reduce(
    const float* __restrict__ part, const float* __restrict__ bias,
    float* __restrict__ wp) {
  const int idx = blockIdx.x * 256 + threadIdx.x;  // (b, m, c), c innermost
  const int c = idx & 255;
  const int m = (idx >> 8) & 31;
  const int b = idx >> 13;
  float s = bias[c];
#pragma unroll
  for (int k = 0; k < 8; ++k)
    s += part[(((size_t)k * 32 + b) * 32 + m) * 256 + c];  // coalesced
  wp[((size_t)b * 256 + c) * 32 + m] = s;
}

// ---------------------------------------------------------------------------
// Stage 2 (R4): R0 structure + wp staged in LDS (kills the scalar-load stall).
// History:
//   R0 (proven 128us): 1 px/thread, 512 blocks, wp via SGPR s_load_dwordx16.
//       Per-wave VALU duty ~21% -- matches 64cy FMA / (~240cy sK$-miss wait)
//       per channel: the SCALAR wp stream is the stall, not image loads.
//   R1-R3: 4-way c-split variants all LOST to R0 (spills at caps 64/48;
//       at VGPR=60 still ~6% duty/wave): same scalar stream, 1/4 the FMAs
//       to hide it. Structure abandoned.
// R4: identical to R0 except wp[b] (32KB) is copied to LDS once per block.
//   Inner-loop wp reads become ds_read_b128 -> VGPR operands: no SGPR budget
//   limit, ~120cy LDS latency pipelined by compiler lgkmcnt batching,
//   uniform-address reads broadcast (zero bank conflicts). No launch-bounds
//   minimum (R1-R3 lesson: never squeeze the allocator); 512 blocks = 2/CU
//   resident needs only VGPR<=256 -- huge slack.
// Global traffic stays optimal: images read once (16-deep nontemporal
// prefetch covers ~900cy HBM latency), outputs written once.
// ---------------------------------------------------------------------------
__global__ __launch_bounds__(256) void attention_fused(
    const float* __restrict__ images, const float* __restrict__ wp,
    const int* __restrict__ maskn, float* __restrict__ out_w,
    float* __restrict__ out_a) {
  __shared__ float lwp[NC_ * MW_];  // 32 KB: wp[b] resident per block
  const int tid = threadIdx.x;
  const int b = blockIdx.x >> 4;
  const int p = ((blockIdx.x & 15) << 8) + tid;
  const float* img = images + (size_t)b * NC_ * HW_ + p;
  const float* wpb = wp + (size_t)b * NC_ * MW_;

  // Stage wp[b] -> LDS (coalesced float4: 2048 vec4 over 256 threads).
  {
    const float4* src = (const float4*)wpb;
    float4* dst = (float4*)lwp;
#pragma unroll
    for (int k = 0; k < 8; ++k) dst[tid + (k << 8)] = src[tid + (k << 8)];
  }
  __syncthreads();

  // scores: s[m] = sum_c img[c,p] * wp[c,m]
  float s[32];
#pragma unroll
  for (int m = 0; m < 32; ++m) s[m] = 0.f;

  float cur[16];
#pragma unroll
  for (int j = 0; j < 16; ++j)
    cur[j] = __builtin_nontemporal_load(img + ((size_t)j << 12));

#pragma unroll 1
  for (int c0 = 0; c0 < 256; c0 += 16) {
    float nxt[16];
    if (c0 + 16 < 256) {
#pragma unroll
      for (int j = 0; j < 16; ++j)
        nxt[j] = __builtin_nontemporal_load(img + ((size_t)(c0 + 16 + j) << 12));
    }
#pragma unroll
    for (int j = 0; j < 16; ++j) {
      const float* wrow = lwp + ((c0 + j) << 5);  // LDS row, broadcast reads
#pragma unroll
      for (int m = 0; m < 32; ++m)
        s[m] = fmaf(cur[j], wrow[m], s[m]);
    }
#pragma unroll
    for (int j = 0; j < 16; ++j) cur[j] = nxt[j];  // dead on last iter
  }

  // mask bits (wave-uniform)
  unsigned mbits = 0;
#pragma unroll
  for (int m = 0; m < 32; ++m)
    mbits |= (maskn[(b << 5) + m] != 0 ? 1u : 0u) << m;

  // softmax over m (scale 1/sqrt(256) = 0.0625); masked -> exactly 0
  float mx = NEG_BIG;
#pragma unroll
  for (int m = 0; m < 32; ++m) {
    s[m] *= 0.0625f;
    if (!((mbits >> m) & 1u)) mx = fmaxf(mx, s[m]);
  }
  float sum = 0.f;
#pragma unroll
  for (int m = 0; m < 32; ++m) {
    const float ev = ((mbits >> m) & 1u) ? 0.f : __expf(s[m] - mx);
    s[m] = ev;
    sum += ev;
  }
  const float inv = 1.f / sum;
#pragma unroll
  for (int m = 0; m < 32; ++m) {
    const float a = s[m] * inv;
    s[m] = a;
    __builtin_nontemporal_store(a, out_a + ((size_t)(b * 32 + m) << 12) + p);
  }

  // weighted words: out[c,p] = sum_m wp[c,m] * a[m]  (wp from LDS)
#pragma unroll 1
  for (int c0 = 0; c0 < 256; c0 += 8) {
#pragma unroll
    for (int jc = 0; jc < 8; ++jc) {
      const int c = c0 + jc;
      const float* wrow = lwp + (c << 5);
      float o = 0.f;
#pragma unroll
      for (int m = 0; m < 32; ++m)
        o = fmaf(wrow[m], s[m], o);
      __builtin_nontemporal_store(o, out_w + ((size_t)(b * 256 + c) << 12) + p);
    }
  }
}

// ---------------------------------------------------------------------------
extern "C" void kernel_launch(void* const* d_in, const int* in_sizes, int n_in,
                              void* d_out, int out_size, void* d_ws, size_t ws_size,
                              hipStream_t stream) {
  const float* images = (const float*)d_in[0];
  const float* words  = (const float*)d_in[1];
  const void*  mask   = d_in[2];
  const float* W      = (const float*)d_in[3];
  const float* bias   = (const float*)d_in[4];

  float* ws     = (float*)d_ws;
  float* part   = ws + PART_OFF;
  float* wp     = ws + WP_OFF;
  float* WT     = ws + WT_OFF;
  float* wordsT = ws + WORDST_OFF;
  int*   maskn  = (int*)(ws + MASK_OFF);

  float* out_w = (float*)d_out;
  float* out_a = out_w + (size_t)B_ * NC_ * HW_;

  prep_kernel<<<961, 256, 0, stream>>>(W, words, mask, WT, wordsT, maskn);
  stage1_partial<<<256, 256, 0, stream>>>(wordsT, WT, part);
  stage1_reduce<<<1024, 256, 0, stream>>>(part, bias, wp);
  attention_fused<<<512, 256, 0, stream>>>(images, wp, maskn, out_w, out_a);
}

// Round 6
// 308.723 us; speedup vs baseline: 1.7665x; 1.0246x over previous
//
#include <hip/hip_runtime.h>
#include <math.h>

// Problem shape (fixed by reference setup_inputs):
//   images [32][256][64][64] fp32, words [32][32][768] fp32, mask [32][32] bool,
//   W [256][768] fp32, b [256] fp32
//   out0 weighted_words [32][256][64][64], out1 attn_out [32][32][64][64], fp32 concat.
#define B_   32
#define NC_  256
#define HW_  4096
#define MW_  32
#define E_   768
#define NEG_BIG -3.0e38f

// Native Clang vector types: __builtin_nontemporal_* accepts these
// (HIP's float2/float4 are classes and are rejected -- R5 compile failure).
typedef float vf2 __attribute__((ext_vector_type(2)));
typedef float vf4 __attribute__((ext_vector_type(4)));

// Workspace layout (float offsets). Total ~13.4 MB.
#define PART_OFF   0          // partial GEMM: 8 chunks * 32b * 32m * 256c = 2097152 floats
#define WP_OFF     2097152    // words_p [b][c][m]: 262144 floats
#define WT_OFF     2359296    // W transposed [e][c]: 196608 floats
#define WORDST_OFF 2555904    // words transposed [b][e][m]: 786432 floats
#define MASK_OFF   3342336    // normalized mask: 1024 ints

// ---------------------------------------------------------------------------
// Prep: tiled transposes (W 256x768 -> WT 768x256; words[b] 32x768 ->
// wordsT[b] 768x32) + mask normalization.
// Blocks 0..191: W transpose. 192..959: words transpose. 960: mask.
// ---------------------------------------------------------------------------
__global__ __launch_bounds__(256) void prep_kernel(
    const float* __restrict__ W, const float* __restrict__ words,
    const void* __restrict__ mask_raw,
    float* __restrict__ WT, float* __restrict__ wordsT,
    int* __restrict__ maskn) {
  const int tid = threadIdx.x;
  const int tx = tid & 31, ty = tid >> 5;
  if (blockIdx.x < 192) {
    // W: 32x32 tile transpose; tiles: 8 (c) x 24 (e)
    __shared__ float t[32][33];
    const int tc = blockIdx.x / 24, te = blockIdx.x % 24;
    const int c0 = tc * 32, e0 = te * 32;
#pragma unroll
    for (int k = 0; k < 4; ++k) {
      const int r = ty + 8 * k;
      t[r][tx] = W[(c0 + r) * E_ + e0 + tx];  // coalesced over tx
    }
    __syncthreads();
#pragma unroll
    for (int k = 0; k < 4; ++k) {
      const int r = ty + 8 * k;
      WT[(e0 + r) * NC_ + c0 + tx] = t[tx][r];  // coalesced over tx
    }
  } else if (blockIdx.x < 960) {
    // words[b]: 32(m) x 768(e) -> wordsT[b]: 768(e) x 32(m). tiles: 32 b x 24 e
    __shared__ float t[32][33];
    const int idx = blockIdx.x - 192;
    const int b = idx / 24, te = idx % 24;
    const int e0 = te * 32;
    const float* wsrc = words + (size_t)b * MW_ * E_;
    float* wdst = wordsT + (size_t)b * E_ * MW_;
#pragma unroll
    for (int k = 0; k < 4; ++k) {
      const int m = ty + 8 * k;
      t[m][tx] = wsrc[m * E_ + e0 + tx];        // coalesced over tx (e)
    }
    __syncthreads();
#pragma unroll
    for (int k = 0; k < 4; ++k) {
      const int e = ty + 8 * k;
      wdst[(e0 + e) * MW_ + tx] = t[tx][e];     // coalesced over tx (m)
    }
  } else {
    // Mask layout detection + normalize to int[1024].
    __shared__ int is_word;  // 1 if 4-byte-per-element layout (int32 or fp32)
    if (tid == 0) is_word = 1;
    __syncthreads();
    const int* mi = (const int*)mask_raw;
    const int v = mi[tid];  // reads only first 1024 bytes: safe for any layout
    if (v != 0 && v != 1 && v != 0x3F800000) is_word = 0;
    __syncthreads();
    if (is_word) {
#pragma unroll
      for (int j = 0; j < 4; ++j) { const int i = j * 256 + tid; maskn[i] = (mi[i] != 0); }
    } else {
      const unsigned char* mb = (const unsigned char*)mask_raw;
#pragma unroll
      for (int j = 0; j < 4; ++j) { const int i = j * 256 + tid; maskn[i] = (mb[i] != 0); }
    }
  }
}

// ---------------------------------------------------------------------------
// Stage 1a: words_p partials. Block = (batch, e-chunk of 96). lane = c.
// ---------------------------------------------------------------------------
__global__ __launch_bounds__(256) void stage1_partial(
    const float* __restrict__ wordsT, const float* __restrict__ WT,
    float* __restrict__ part) {
  const int c = threadIdx.x;
  const int b = blockIdx.x >> 3;
  const int chunk = blockIdx.x & 7;
  const int e0 = chunk * 96;
  const float* wt = wordsT + (size_t)b * E_ * MW_;
  float acc[32];
#pragma unroll
  for (int m = 0; m < 32; ++m) acc[m] = 0.f;
#pragma unroll 2
  for (int e = e0; e < e0 + 96; ++e) {
    const float wv = WT[(size_t)e * NC_ + c];   // coalesced over lanes
    const float* wr = wt + e * MW_;             // uniform, contiguous
#pragma unroll
    for (int m = 0; m < 32; ++m) acc[m] = fmaf(wv, wr[m], acc[m]);
  }
  float* pp = part + ((size_t)chunk * 32 + b) * 32 * 256;
#pragma unroll
  for (int m = 0; m < 32; ++m) pp[m * 256 + c] = acc[m];  // coalesced
}

// ---------------------------------------------------------------------------
// Stage 1b: reduce 8 partials + bias -> wp[b][c][m] (m contiguous for stage 2).
// ---------------------------------------------------------------------------
__global__ __launch_bounds__(256) void stage1_reduce(
    const float* __restrict__ part, const float* __restrict__ bias,
    float* __restrict__ wp) {
  const int idx = blockIdx.x * 256 + threadIdx.x;  // (b, m, c), c innermost
  const int c = idx & 255;
  const int m = (idx >> 8) & 31;
  const int b = idx >> 13;
  float s = bias[c];
#pragma unroll
  for (int k = 0; k < 8; ++k)
    s += part[(((size_t)k * 32 + b) * 32 + m) * 256 + c];  // coalesced
  wp[((size_t)b * 256 + c) * 32 + m] = s;
}

// ---------------------------------------------------------------------------
// Stage 2 (R6 = R5 with the nontemporal-vector-type compile fix):
// LDS-wp + 2 px/thread (native ext_vector float2) to fix the LDS-pipe limit.
// History:
//   R0 (128us): wp via s_load: scalar-stream stall, 21% duty/wave.
//   R1-R3: c-split variants: allocator squeeze -> spills. Abandoned.
//   R4 (102us): wp in LDS, 47% VALU. New wall: per channel a wave issues
//       8 ds_read_b128 per 32 FMA-insts; 8 waves/CU -> ~1 ds_read/cyc
//       demanded of the one LDS pipe -> LDS-issue bound at ~50% duty.
//   R5: compile fail (__builtin_nontemporal_* rejects HIP_vector_type).
// R6: 2 px/thread via vf2 lanes. wrow reads shared across the px pair ->
//   read:FMA ratio halves (1 b128 : 8 FMA-insts). 512 blocks x 128 thr
//   (2 blocks/CU, 4 waves/CU, 1/SIMD): LDS demand 32 reads per 128-cyc FMA
//   wall = 1/4cyc <= broadcast throughput. Latency hiding is ILP: 16-deep
//   vf2 prefetch = 2048 FMA-cyc covers ~900-cyc HBM misses. Launch bounds
//   (128,1): VGPR cap 512, live ~160 -> NO allocator squeeze (R1-R3 lesson).
//   Img prefetch issued BEFORE wp staging (overlap). vf2 also halves
//   img-load/store instruction counts and wp staging instructions.
// Global traffic optimal: images once, outputs once, wp 16 MB L2 reads.
// ---------------------------------------------------------------------------
__global__ __launch_bounds__(128, 1) void attention_fused(
    const float* __restrict__ images, const float* __restrict__ wp,
    const int* __restrict__ maskn, float* __restrict__ out_w,
    float* __restrict__ out_a) {
  __shared__ float lwp[NC_ * MW_];  // 32 KB: wp[b] resident per block
  const int tid = threadIdx.x;           // 0..127
  const int b = blockIdx.x & 31;         // batch-minor: CU/XCD-mates share b
  const int po = ((blockIdx.x >> 5) << 7) + tid;  // vf2 idx in [0,2048)
  const vf2* imgb = (const vf2*)(images + (size_t)b * NC_ * HW_);

  // Issue image prefetch FIRST -- flies during the LDS staging below.
  vf2 cur[16];
#pragma unroll
  for (int j = 0; j < 16; ++j)
    cur[j] = __builtin_nontemporal_load(&imgb[((size_t)j << 11) + po]);

  // Stage wp[b] -> LDS (2048 vf4 over 128 threads, coalesced).
  {
    const vf4* src = (const vf4*)(wp + (size_t)b * NC_ * MW_);
    vf4* dst = (vf4*)lwp;
#pragma unroll
    for (int k = 0; k < 16; ++k) dst[tid + (k << 7)] = src[tid + (k << 7)];
  }
  __syncthreads();

  // scores for the pixel pair: s{0,1}[m] = sum_c img[c,p{0,1}] * wp[c,m]
  float s0[32], s1[32];
#pragma unroll
  for (int m = 0; m < 32; ++m) { s0[m] = 0.f; s1[m] = 0.f; }

#pragma unroll 1
  for (int c0 = 0; c0 < 256; c0 += 16) {
    vf2 nxt[16];
    if (c0 + 16 < 256) {
#pragma unroll
      for (int j = 0; j < 16; ++j)
        nxt[j] = __builtin_nontemporal_load(&imgb[((size_t)(c0 + 16 + j) << 11) + po]);
    }
#pragma unroll
    for (int j = 0; j < 16; ++j) {
      const float* wrow = lwp + ((c0 + j) << 5);  // broadcast LDS row
      const vf2 v = cur[j];
#pragma unroll
      for (int m = 0; m < 32; ++m) {
        s0[m] = fmaf(v.x, wrow[m], s0[m]);
        s1[m] = fmaf(v.y, wrow[m], s1[m]);
      }
    }
#pragma unroll
    for (int j = 0; j < 16; ++j) cur[j] = nxt[j];  // dead on last iter
  }

  // mask bits (wave-uniform)
  unsigned mbits = 0;
#pragma unroll
  for (int m = 0; m < 32; ++m)
    mbits |= (maskn[(b << 5) + m] != 0 ? 1u : 0u) << m;

  // softmax over m for both pixels (scale 1/sqrt(256)); masked -> exactly 0
  float mx0 = NEG_BIG, mx1 = NEG_BIG;
#pragma unroll
  for (int m = 0; m < 32; ++m) {
    s0[m] *= 0.0625f;
    s1[m] *= 0.0625f;
    if (!((mbits >> m) & 1u)) {
      mx0 = fmaxf(mx0, s0[m]);
      mx1 = fmaxf(mx1, s1[m]);
    }
  }
  float sum0 = 0.f, sum1 = 0.f;
#pragma unroll
  for (int m = 0; m < 32; ++m) {
    const bool msk = (mbits >> m) & 1u;
    const float e0 = msk ? 0.f : __expf(s0[m] - mx0);
    const float e1 = msk ? 0.f : __expf(s1[m] - mx1);
    s0[m] = e0; s1[m] = e1;
    sum0 += e0; sum1 += e1;
  }
  const float inv0 = 1.f / sum0, inv1 = 1.f / sum1;
  vf2* oa = (vf2*)out_a;
#pragma unroll
  for (int m = 0; m < 32; ++m) {
    s0[m] *= inv0;
    s1[m] *= inv1;
    vf2 a; a.x = s0[m]; a.y = s1[m];
    __builtin_nontemporal_store(a, &oa[((size_t)((b << 5) + m) << 11) + po]);
  }

  // weighted words: out[c,p] = sum_m wp[c,m] * a[m]  (wp rows shared by pair)
  vf2* ow = (vf2*)out_w;
#pragma unroll 1
  for (int c0 = 0; c0 < 256; c0 += 8) {
#pragma unroll
    for (int jc = 0; jc < 8; ++jc) {
      const int c = c0 + jc;
      const float* wrow = lwp + (c << 5);
      float o0 = 0.f, o1 = 0.f;
#pragma unroll
      for (int m = 0; m < 32; ++m) {
        o0 = fmaf(wrow[m], s0[m], o0);
        o1 = fmaf(wrow[m], s1[m], o1);
      }
      vf2 o; o.x = o0; o.y = o1;
      __builtin_nontemporal_store(o, &ow[((size_t)((b << 8) + c) << 11) + po]);
    }
  }
}

// ---------------------------------------------------------------------------
extern "C" void kernel_launch(void* const* d_in, const int* in_sizes, int n_in,
                              void* d_out, int out_size, void* d_ws, size_t ws_size,
                              hipStream_t stream) {
  const float* images = (const float*)d_in[0];
  const float* words  = (const float*)d_in[1];
  const void*  mask   = d_in[2];
  const float* W      = (const float*)d_in[3];
  const float* bias   = (const float*)d_in[4];

  float* ws     = (float*)d_ws;
  float* part   = ws + PART_OFF;
  float* wp     = ws + WP_OFF;
  float* WT     = ws + WT_OFF;
  float* wordsT = ws + WORDST_OFF;
  int*   maskn  = (int*)(ws + MASK_OFF);

  float* out_w = (float*)d_out;
  float* out_a = out_w + (size_t)B_ * NC_ * HW_;

  prep_kernel<<<961, 256, 0, stream>>>(W, words, mask, WT, wordsT, maskn);
  stage1_partial<<<256, 256, 0, stream>>>(wordsT, WT, part);
  stage1_reduce<<<1024, 256, 0, stream>>>(part, bias, wp);
  attention_fused<<<512, 128, 0, stream>>>(images, wp, maskn, out_w, out_a);
}